// Round 3
// baseline (503.877 us; speedup 1.0000x reference)
//
#include <hip/hip_runtime.h>

// Voxelizer3D: out[f][z][y][x] = sum over masked atoms (all coords != 0) whose
// center cell is within Chebyshev distance 1 of (x,y,z), of feat[a][f].
// v3: no global atomics. Pipeline: minmax -> per-atom packed cell ->
// region-gather into LDS histogram + fused 3x3x3 box conv.

constexpr int VOL   = 48;
constexpr int FEATD = 19;
constexpr int RY = 4, RZ = 4;               // region size in y,z (x spans full 48)
constexpr int NRY = VOL / RY;               // 12
constexpr int NRZ = VOL / RZ;               // 12
constexpr int NREG = NRY * NRZ;             // 144 regions
constexpr int HX = VOL + 2;                 // x stored with halo: 50
constexpr int HY = RY + 2, HZ = RZ + 2;     // 6, 6
constexpr int FG = 7;                       // max features per group (7,6,6)
constexpr unsigned SENT = 0xFFFFFFFFu;

__device__ __forceinline__ unsigned fkey(float f) {
    unsigned u = __float_as_uint(f);
    return (u & 0x80000000u) ? ~u : (u | 0x80000000u);
}
__device__ __forceinline__ float funkey(unsigned k) {
    unsigned u = (k & 0x80000000u) ? (k & 0x7fffffffu) : ~k;
    return __uint_as_float(u);
}

// ---- stage 1: min/max of masked coords ----
__global__ __launch_bounds__(1024) void vox_minmax(const float* __restrict__ xyz,
                                                   int n, unsigned* __restrict__ keys) {
    __shared__ unsigned smin[16][3], smax[16][3];
    unsigned kmin[3] = {~0u, ~0u, ~0u};
    unsigned kmax[3] = {0u, 0u, 0u};
    for (int i = blockIdx.x * blockDim.x + threadIdx.x; i < n;
         i += gridDim.x * blockDim.x) {
        float x = xyz[3 * i + 0], y = xyz[3 * i + 1], z = xyz[3 * i + 2];
        if (x != 0.f && y != 0.f && z != 0.f) {
            unsigned k[3] = {fkey(x), fkey(y), fkey(z)};
            #pragma unroll
            for (int c = 0; c < 3; c++) {
                kmin[c] = kmin[c] < k[c] ? kmin[c] : k[c];
                kmax[c] = kmax[c] > k[c] ? kmax[c] : k[c];
            }
        }
    }
    #pragma unroll
    for (int o = 32; o; o >>= 1) {
        #pragma unroll
        for (int c = 0; c < 3; c++) {
            unsigned omin = __shfl_xor(kmin[c], o, 64);
            unsigned omax = __shfl_xor(kmax[c], o, 64);
            kmin[c] = kmin[c] < omin ? kmin[c] : omin;
            kmax[c] = kmax[c] > omax ? kmax[c] : omax;
        }
    }
    int wave = threadIdx.x >> 6;
    if ((threadIdx.x & 63) == 0) {
        #pragma unroll
        for (int c = 0; c < 3; c++) { smin[wave][c] = kmin[c]; smax[wave][c] = kmax[c]; }
    }
    __syncthreads();
    if (threadIdx.x == 0) {
        int nw = blockDim.x >> 6;
        #pragma unroll
        for (int c = 0; c < 3; c++) { kmin[c] = smin[0][c]; kmax[c] = smax[0][c]; }
        for (int w = 1; w < nw; w++) {
            #pragma unroll
            for (int c = 0; c < 3; c++) {
                kmin[c] = kmin[c] < smin[w][c] ? kmin[c] : smin[w][c];
                kmax[c] = kmax[c] > smax[w][c] ? kmax[c] : smax[w][c];
            }
        }
        #pragma unroll
        for (int c = 0; c < 3; c++) {
            atomicMin(&keys[c], kmin[c]);
            atomicMax(&keys[3 + c], kmax[c]);
        }
    }
}

// ---- stage 2: per-atom packed center cell (SENT if masked out) ----
__global__ void vox_cells(const float* __restrict__ xyz, int n,
                          const unsigned* __restrict__ keys,
                          unsigned* __restrict__ cells) {
    int i = blockIdx.x * blockDim.x + threadIdx.x;
    if (i >= n) return;
    float x = xyz[3 * i + 0], y = xyz[3 * i + 1], z = xyz[3 * i + 2];
    unsigned packed = SENT;
    if (x != 0.f && y != 0.f && z != 0.f) {
        float mnx = funkey(keys[0]), mny = funkey(keys[1]), mnz = funkey(keys[2]);
        float mxx = funkey(keys[3]), mxy = funkey(keys[4]), mxz = funkey(keys[5]);
        // exact op-order of reference: (x - min) / (max - min) * 47, f32, truncate
        int cx = (int)((x - mnx) / (mxx - mnx) * 47.0f);
        int cy = (int)((y - mny) / (mxy - mny) * 47.0f);
        int cz = (int)((z - mnz) / (mxz - mnz) * 47.0f);
        packed = ((unsigned)cz << 12) | ((unsigned)cy << 6) | (unsigned)cx;
    }
    cells[i] = packed;
}

// ---- stage 3: region gather into LDS histogram + fused 3x3x3 conv ----
__global__ __launch_bounds__(256) void vox_gather(const unsigned* __restrict__ cells,
                                                  const float* __restrict__ feat,
                                                  int n, float* __restrict__ out) {
    __shared__ float hist[HZ * HY * HX * FG];   // 6*6*50*7 = 12600 floats = 50.4 KB
    const int region = blockIdx.x;              // 0..143
    const int g = blockIdx.y;                   // 0..2 feature group
    const int ry = region % NRY, rz = region / NRY;
    const int fbase = (g == 0) ? 0 : (7 + (g - 1) * 6);
    const int fg = (g == 0) ? 7 : 6;
    const int y0 = ry * RY - 1, z0 = rz * RZ - 1;   // halo origin in grid coords

    for (int i = threadIdx.x; i < HZ * HY * HX * FG; i += blockDim.x) hist[i] = 0.f;
    __syncthreads();

    // scan all atoms' packed cells (coalesced, L2-resident)
    const uint4* c4 = (const uint4*)cells;
    const int n4 = n >> 2;
    for (int i = threadIdx.x; i < n4; i += blockDim.x) {
        uint4 cc = c4[i];
        unsigned arr[4] = {cc.x, cc.y, cc.z, cc.w};
        #pragma unroll
        for (int k = 0; k < 4; k++) {
            unsigned c = arr[k];
            if (c == SENT) continue;
            int cx = c & 63, cy = (c >> 6) & 63, cz = (c >> 12) & 63;
            int ly = cy - y0, lz = cz - z0;
            if ((unsigned)ly >= (unsigned)HY || (unsigned)lz >= (unsigned)HZ) continue;
            const float* fr = feat + (size_t)(i * 4 + k) * FEATD + fbase;
            float* h = &hist[(((lz * HY) + ly) * HX + (cx + 1)) * FG];
            for (int f = 0; f < fg; f++) atomicAdd(&h[f], fr[f]);
        }
    }
    __syncthreads();

    // conv: each output (f, z, y, x) in region = sum of 27 LDS neighbors
    const int total = fg * RZ * RY * VOL;
    for (int t = threadIdx.x; t < total; t += blockDim.x) {
        int x = t % VOL;
        int r = t / VOL;
        int y = r % RY; r /= RY;
        int z = r % RZ;
        int f = r / RZ;
        float s = 0.f;
        #pragma unroll
        for (int dz = 0; dz < 3; dz++)
            #pragma unroll
            for (int dy = 0; dy < 3; dy++) {
                const float* row = &hist[(((z + dz) * HY + (y + dy)) * HX + x) * FG + f];
                s += row[0] + row[FG] + row[2 * FG];
            }
        int gy = ry * RY + y, gz = rz * RZ + z;
        out[(((size_t)(fbase + f) * VOL + gz) * VOL + gy) * VOL + x] = s;
    }
}

extern "C" void kernel_launch(void* const* d_in, const int* in_sizes, int n_in,
                              void* d_out, int out_size, void* d_ws, size_t ws_size,
                              hipStream_t stream) {
    const float* xyz  = (const float*)d_in[0];
    const float* feat = (const float*)d_in[1];
    float* out = (float*)d_out;
    int n = in_sizes[0] / 3;

    unsigned* keys  = (unsigned*)d_ws;
    unsigned* cells = (unsigned*)((char*)d_ws + 256);

    // workspace re-init every call (harness does not re-poison)
    hipMemsetAsync(keys, 0xFF, 3 * sizeof(unsigned), stream);
    hipMemsetAsync(keys + 3, 0x00, 3 * sizeof(unsigned), stream);

    vox_minmax<<<64, 1024, 0, stream>>>(xyz, n, keys);

    const int b = 256;
    vox_cells<<<(n + b - 1) / b, b, 0, stream>>>(xyz, n, keys, cells);

    dim3 gg(NREG, 3);
    vox_gather<<<gg, b, 0, stream>>>(cells, feat, n, out);
}

// Round 4
// 131.987 us; speedup vs baseline: 3.8176x; 3.8176x over previous
//
#include <hip/hip_runtime.h>

// Voxelizer3D: out[f][z][y][x] = sum over masked atoms (all coords != 0) whose
// center cell is within Chebyshev distance 1 of (x,y,z), of feat[a][f].
// v4: counting-sort (CSR) pipeline -> zero float atomics, balanced gather.
//   minmax -> cells+count -> 3-phase scan -> place -> per-cell accum -> conv.

constexpr int VOL   = 48;
constexpr int FEATD = 19;
constexpr int VOL3  = VOL * VOL * VOL;      // 110592
constexpr int SCB   = 256;                  // scan block size
constexpr int NSB   = VOL3 / SCB;           // 432 scan blocks (exact)
constexpr unsigned SENT = 0xFFFFFFFFu;

__device__ __forceinline__ unsigned fkey(float f) {
    unsigned u = __float_as_uint(f);
    return (u & 0x80000000u) ? ~u : (u | 0x80000000u);
}
__device__ __forceinline__ float funkey(unsigned k) {
    unsigned u = (k & 0x80000000u) ? (k & 0x7fffffffu) : ~k;
    return __uint_as_float(u);
}

// ---- stage 1: min/max of masked coords; also zeroes the count array ----
__global__ __launch_bounds__(1024) void vox_minmax(const float* __restrict__ xyz,
                                                   int n, unsigned* __restrict__ keys,
                                                   unsigned* __restrict__ counts) {
    if (counts) {
        for (int j = blockIdx.x * blockDim.x + threadIdx.x; j < VOL3;
             j += gridDim.x * blockDim.x) counts[j] = 0u;
    }
    __shared__ unsigned smin[16][3], smax[16][3];
    unsigned kmin[3] = {~0u, ~0u, ~0u};
    unsigned kmax[3] = {0u, 0u, 0u};
    for (int i = blockIdx.x * blockDim.x + threadIdx.x; i < n;
         i += gridDim.x * blockDim.x) {
        float x = xyz[3 * i + 0], y = xyz[3 * i + 1], z = xyz[3 * i + 2];
        if (x != 0.f && y != 0.f && z != 0.f) {
            unsigned k[3] = {fkey(x), fkey(y), fkey(z)};
            #pragma unroll
            for (int c = 0; c < 3; c++) {
                kmin[c] = kmin[c] < k[c] ? kmin[c] : k[c];
                kmax[c] = kmax[c] > k[c] ? kmax[c] : k[c];
            }
        }
    }
    #pragma unroll
    for (int o = 32; o; o >>= 1) {
        #pragma unroll
        for (int c = 0; c < 3; c++) {
            unsigned omin = __shfl_xor(kmin[c], o, 64);
            unsigned omax = __shfl_xor(kmax[c], o, 64);
            kmin[c] = kmin[c] < omin ? kmin[c] : omin;
            kmax[c] = kmax[c] > omax ? kmax[c] : omax;
        }
    }
    int wave = threadIdx.x >> 6;
    if ((threadIdx.x & 63) == 0) {
        #pragma unroll
        for (int c = 0; c < 3; c++) { smin[wave][c] = kmin[c]; smax[wave][c] = kmax[c]; }
    }
    __syncthreads();
    if (threadIdx.x == 0) {
        int nw = blockDim.x >> 6;
        #pragma unroll
        for (int c = 0; c < 3; c++) { kmin[c] = smin[0][c]; kmax[c] = smax[0][c]; }
        for (int w = 1; w < nw; w++) {
            #pragma unroll
            for (int c = 0; c < 3; c++) {
                kmin[c] = kmin[c] < smin[w][c] ? kmin[c] : smin[w][c];
                kmax[c] = kmax[c] > smax[w][c] ? kmax[c] : smax[w][c];
            }
        }
        #pragma unroll
        for (int c = 0; c < 3; c++) {
            atomicMin(&keys[c], kmin[c]);
            atomicMax(&keys[3 + c], kmax[c]);
        }
    }
}

// ---- stage 2: per-atom linear cell id + count histogram ----
__global__ void vox_cells_count(const float* __restrict__ xyz, int n,
                                const unsigned* __restrict__ keys,
                                unsigned* __restrict__ cells,
                                unsigned* __restrict__ counts) {
    int i = blockIdx.x * blockDim.x + threadIdx.x;
    if (i >= n) return;
    float x = xyz[3 * i + 0], y = xyz[3 * i + 1], z = xyz[3 * i + 2];
    unsigned cell = SENT;
    if (x != 0.f && y != 0.f && z != 0.f) {
        float mnx = funkey(keys[0]), mny = funkey(keys[1]), mnz = funkey(keys[2]);
        float mxx = funkey(keys[3]), mxy = funkey(keys[4]), mxz = funkey(keys[5]);
        // exact op-order of reference: (x - min) / (max - min) * 47, f32, truncate
        int cx = (int)((x - mnx) / (mxx - mnx) * 47.0f);
        int cy = (int)((y - mny) / (mxy - mny) * 47.0f);
        int cz = (int)((z - mnz) / (mxz - mnz) * 47.0f);
        cell = (unsigned)((cz * VOL + cy) * VOL + cx);
        atomicAdd(&counts[cell], 1u);
    }
    cells[i] = cell;
}

// ---- stage 3: exclusive prefix scan of counts (3 launches) ----
__global__ __launch_bounds__(SCB) void vox_scan_a(const unsigned* __restrict__ counts,
                                                  unsigned* __restrict__ offsets,
                                                  unsigned* __restrict__ bsums) {
    __shared__ unsigned s[SCB];
    int gid = blockIdx.x * SCB + threadIdx.x;
    unsigned c = counts[gid];
    s[threadIdx.x] = c;
    __syncthreads();
    for (int off = 1; off < SCB; off <<= 1) {
        unsigned v = 0;
        if ((int)threadIdx.x >= off) v = s[threadIdx.x - off];
        __syncthreads();
        if ((int)threadIdx.x >= off) s[threadIdx.x] += v;
        __syncthreads();
    }
    offsets[gid] = s[threadIdx.x] - c;          // exclusive within block
    if (threadIdx.x == SCB - 1) bsums[blockIdx.x] = s[threadIdx.x];
}

__global__ __launch_bounds__(512) void vox_scan_b(unsigned* __restrict__ bsums,
                                                  unsigned* __restrict__ boffs) {
    __shared__ unsigned s[512];
    unsigned c = (threadIdx.x < NSB) ? bsums[threadIdx.x] : 0u;
    s[threadIdx.x] = c;
    __syncthreads();
    for (int off = 1; off < 512; off <<= 1) {
        unsigned v = 0;
        if ((int)threadIdx.x >= off) v = s[threadIdx.x - off];
        __syncthreads();
        if ((int)threadIdx.x >= off) s[threadIdx.x] += v;
        __syncthreads();
    }
    if (threadIdx.x < NSB) boffs[threadIdx.x] = s[threadIdx.x] - c;
}

__global__ __launch_bounds__(SCB) void vox_scan_c(unsigned* __restrict__ offsets,
                                                  const unsigned* __restrict__ boffs) {
    int gid = blockIdx.x * SCB + threadIdx.x;
    offsets[gid] += boffs[blockIdx.x];
}

// ---- stage 4: place atom indices into CSR order; offsets become end-ptrs ----
__global__ void vox_place(const unsigned* __restrict__ cells, int n,
                          unsigned* __restrict__ offsets,
                          unsigned* __restrict__ order) {
    int i = blockIdx.x * blockDim.x + threadIdx.x;
    if (i >= n) return;
    unsigned c = cells[i];
    if (c == SENT) return;
    unsigned slot = atomicAdd(&offsets[c], 1u);
    order[slot] = (unsigned)i;
}

// ---- stage 5: per-cell feature accumulation (no atomics) ----
__global__ __launch_bounds__(SCB) void vox_accum(const unsigned* __restrict__ order,
                                                 const unsigned* __restrict__ offsets,
                                                 const unsigned* __restrict__ counts,
                                                 const float* __restrict__ feat,
                                                 float* __restrict__ center) {
    int cell = blockIdx.x * SCB + threadIdx.x;
    unsigned cnt = counts[cell];
    unsigned end = offsets[cell];               // after place: start + cnt
    unsigned base = end - cnt;
    float acc[FEATD];
    #pragma unroll
    for (int f = 0; f < FEATD; f++) acc[f] = 0.f;
    for (unsigned k = 0; k < cnt; k++) {
        unsigned a = order[base + k];
        const float* fr = feat + (size_t)a * FEATD;
        #pragma unroll
        for (int f = 0; f < FEATD; f++) acc[f] += fr[f];
    }
    #pragma unroll
    for (int f = 0; f < FEATD; f++)
        center[(size_t)f * VOL3 + cell] = acc[f];
}

// ---- stage 6: 3x3x3 box convolution ----
__global__ void vox_conv(const float* __restrict__ center,
                         float* __restrict__ out, int total) {
    int idx = blockIdx.x * blockDim.x + threadIdx.x;
    if (idx >= total) return;
    int x = idx % VOL;
    int t = idx / VOL;
    int y = t % VOL;  t /= VOL;
    int z = t % VOL;
    int f = t / VOL;
    const float* cf = center + (size_t)f * VOL3;
    float s = 0.f;
    for (int dz = -1; dz <= 1; dz++) {
        int zz = z + dz; if ((unsigned)zz >= (unsigned)VOL) continue;
        for (int dy = -1; dy <= 1; dy++) {
            int yy = y + dy; if ((unsigned)yy >= (unsigned)VOL) continue;
            const float* row = cf + (zz * VOL + yy) * VOL;
            #pragma unroll
            for (int dx = -1; dx <= 1; dx++) {
                int xx = x + dx; if ((unsigned)xx >= (unsigned)VOL) continue;
                s += row[xx];
            }
        }
    }
    out[idx] = s;
}

// ---- fallback: direct scatter (if ws too small) ----
__global__ void vox_scatter_lin(const float* __restrict__ xyz,
                                const float* __restrict__ feat, int n,
                                const unsigned* __restrict__ keys,
                                float* __restrict__ center) {
    int i = blockIdx.x * blockDim.x + threadIdx.x;
    if (i >= n) return;
    float x = xyz[3 * i + 0], y = xyz[3 * i + 1], z = xyz[3 * i + 2];
    if (x == 0.f || y == 0.f || z == 0.f) return;
    float mnx = funkey(keys[0]), mny = funkey(keys[1]), mnz = funkey(keys[2]);
    float mxx = funkey(keys[3]), mxy = funkey(keys[4]), mxz = funkey(keys[5]);
    int cx = (int)((x - mnx) / (mxx - mnx) * 47.0f);
    int cy = (int)((y - mny) / (mxy - mny) * 47.0f);
    int cz = (int)((z - mnz) / (mxz - mnz) * 47.0f);
    int cell = (cz * VOL + cy) * VOL + cx;
    const float* fr = feat + (size_t)i * FEATD;
    #pragma unroll
    for (int f = 0; f < FEATD; f++)
        atomicAdd(&center[f * VOL3 + cell], fr[f]);
}

extern "C" void kernel_launch(void* const* d_in, const int* in_sizes, int n_in,
                              void* d_out, int out_size, void* d_ws, size_t ws_size,
                              hipStream_t stream) {
    const float* xyz  = (const float*)d_in[0];
    const float* feat = (const float*)d_in[1];
    float* out = (float*)d_out;
    int n = in_sizes[0] / 3;

    char* w = (char*)d_ws;
    unsigned* keys    = (unsigned*)w;                       // 24 B (pad 256)
    unsigned* cells   = (unsigned*)(w + 256);               // n*4
    size_t o1 = 256 + (size_t)n * 4;
    unsigned* counts  = (unsigned*)(w + o1);                // VOL3*4
    size_t o2 = o1 + (size_t)VOL3 * 4;
    unsigned* offsets = (unsigned*)(w + o2);                // VOL3*4
    size_t o3 = o2 + (size_t)VOL3 * 4;
    unsigned* bsums   = (unsigned*)(w + o3);                // 512*4
    unsigned* boffs   = bsums + 512;                        // 512*4
    size_t o4 = o3 + 4096;
    unsigned* order   = (unsigned*)(w + o4);                // n*4
    size_t o5 = o4 + (size_t)n * 4;
    float* center     = (float*)(w + o5);                   // FEATD*VOL3*4
    size_t need = o5 + (size_t)FEATD * VOL3 * 4;

    hipMemsetAsync(keys, 0xFF, 3 * sizeof(unsigned), stream);
    hipMemsetAsync(keys + 3, 0x00, 3 * sizeof(unsigned), stream);

    const int b = 256;
    const int total = FEATD * VOL3;

    if (ws_size >= need) {
        vox_minmax<<<64, 1024, 0, stream>>>(xyz, n, keys, counts);
        vox_cells_count<<<(n + b - 1) / b, b, 0, stream>>>(xyz, n, keys, cells, counts);
        vox_scan_a<<<NSB, SCB, 0, stream>>>(counts, offsets, bsums);
        vox_scan_b<<<1, 512, 0, stream>>>(bsums, boffs);
        vox_scan_c<<<NSB, SCB, 0, stream>>>(offsets, boffs);
        vox_place<<<(n + b - 1) / b, b, 0, stream>>>(cells, n, offsets, order);
        vox_accum<<<NSB, SCB, 0, stream>>>(order, offsets, counts, feat, center);
        vox_conv<<<(total + b - 1) / b, b, 0, stream>>>(center, out, total);
    } else {
        float* c2 = (float*)(w + 256);
        vox_minmax<<<64, 1024, 0, stream>>>(xyz, n, keys, (unsigned*)nullptr);
        hipMemsetAsync(c2, 0, (size_t)FEATD * VOL3 * 4, stream);
        vox_scatter_lin<<<(n + b - 1) / b, b, 0, stream>>>(xyz, feat, n, keys, c2);
        vox_conv<<<(total + b - 1) / b, b, 0, stream>>>(c2, out, total);
    }
}

// Round 5
// 95.144 us; speedup vs baseline: 5.2959x; 1.3872x over previous
//
#include <hip/hip_runtime.h>

// Voxelizer3D: out[f][z][y][x] = sum over masked atoms (all coords != 0) whose
// center cell is within Chebyshev distance 1 of (x,y,z), of feat[a][f].
// v5: CSR pipeline, MLP-batched accum, fused scan_c+place, fewer dispatches.
//   init -> minmax(+zero counts) -> cells+count -> scan_a -> scan_b ->
//   place(+boffs) -> accum(8-deep MLP) -> conv(z-rolling).

constexpr int VOL   = 48;
constexpr int FEATD = 19;
constexpr int VOL3  = VOL * VOL * VOL;      // 110592
constexpr int SCB   = 256;                  // scan block size
constexpr int NSB   = VOL3 / SCB;           // 432 scan blocks (exact)
constexpr int ZK    = 4;                    // z outputs per conv thread
constexpr unsigned SENT = 0xFFFFFFFFu;

__device__ __forceinline__ unsigned fkey(float f) {
    unsigned u = __float_as_uint(f);
    return (u & 0x80000000u) ? ~u : (u | 0x80000000u);
}
__device__ __forceinline__ float funkey(unsigned k) {
    unsigned u = (k & 0x80000000u) ? (k & 0x7fffffffu) : ~k;
    return __uint_as_float(u);
}

// ---- stage 0: init keys (replaces two memsets) ----
__global__ void vox_init(unsigned* __restrict__ keys) {
    int t = threadIdx.x;
    if (t < 3) keys[t] = ~0u;
    else if (t < 6) keys[t] = 0u;
}

// ---- stage 1: min/max of masked coords; also zeroes the count array ----
__global__ __launch_bounds__(1024) void vox_minmax(const float* __restrict__ xyz,
                                                   int n, unsigned* __restrict__ keys,
                                                   unsigned* __restrict__ counts) {
    for (int j = blockIdx.x * blockDim.x + threadIdx.x; j < VOL3;
         j += gridDim.x * blockDim.x) counts[j] = 0u;

    __shared__ unsigned smin[16][3], smax[16][3];
    unsigned kmin[3] = {~0u, ~0u, ~0u};
    unsigned kmax[3] = {0u, 0u, 0u};
    const int nq = n >> 2;                  // quads of atoms
    const float4* p4 = (const float4*)xyz;
    for (int q = blockIdx.x * blockDim.x + threadIdx.x; q < nq;
         q += gridDim.x * blockDim.x) {
        float4 v0 = p4[3 * q], v1 = p4[3 * q + 1], v2 = p4[3 * q + 2];
        float ax[4] = {v0.x, v0.w, v1.z, v2.y};
        float ay[4] = {v0.y, v1.x, v1.w, v2.z};
        float az[4] = {v0.z, v1.y, v2.x, v2.w};
        #pragma unroll
        for (int k = 0; k < 4; k++) {
            if (ax[k] != 0.f && ay[k] != 0.f && az[k] != 0.f) {
                unsigned kk[3] = {fkey(ax[k]), fkey(ay[k]), fkey(az[k])};
                #pragma unroll
                for (int c = 0; c < 3; c++) {
                    kmin[c] = kmin[c] < kk[c] ? kmin[c] : kk[c];
                    kmax[c] = kmax[c] > kk[c] ? kmax[c] : kk[c];
                }
            }
        }
    }
    // tail atoms
    for (int i = (nq << 2) + blockIdx.x * blockDim.x + threadIdx.x; i < n;
         i += gridDim.x * blockDim.x) {
        float x = xyz[3 * i], y = xyz[3 * i + 1], z = xyz[3 * i + 2];
        if (x != 0.f && y != 0.f && z != 0.f) {
            unsigned kk[3] = {fkey(x), fkey(y), fkey(z)};
            #pragma unroll
            for (int c = 0; c < 3; c++) {
                kmin[c] = kmin[c] < kk[c] ? kmin[c] : kk[c];
                kmax[c] = kmax[c] > kk[c] ? kmax[c] : kk[c];
            }
        }
    }
    #pragma unroll
    for (int o = 32; o; o >>= 1) {
        #pragma unroll
        for (int c = 0; c < 3; c++) {
            unsigned omin = __shfl_xor(kmin[c], o, 64);
            unsigned omax = __shfl_xor(kmax[c], o, 64);
            kmin[c] = kmin[c] < omin ? kmin[c] : omin;
            kmax[c] = kmax[c] > omax ? kmax[c] : omax;
        }
    }
    int wave = threadIdx.x >> 6;
    if ((threadIdx.x & 63) == 0) {
        #pragma unroll
        for (int c = 0; c < 3; c++) { smin[wave][c] = kmin[c]; smax[wave][c] = kmax[c]; }
    }
    __syncthreads();
    if (threadIdx.x == 0) {
        int nw = blockDim.x >> 6;
        #pragma unroll
        for (int c = 0; c < 3; c++) { kmin[c] = smin[0][c]; kmax[c] = smax[0][c]; }
        for (int w = 1; w < nw; w++) {
            #pragma unroll
            for (int c = 0; c < 3; c++) {
                kmin[c] = kmin[c] < smin[w][c] ? kmin[c] : smin[w][c];
                kmax[c] = kmax[c] > smax[w][c] ? kmax[c] : smax[w][c];
            }
        }
        #pragma unroll
        for (int c = 0; c < 3; c++) {
            atomicMin(&keys[c], kmin[c]);
            atomicMax(&keys[3 + c], kmax[c]);
        }
    }
}

// ---- stage 2: per-atom linear cell id + count histogram (4 atoms/thread) ----
__global__ void vox_cells_count(const float* __restrict__ xyz, int n,
                                const unsigned* __restrict__ keys,
                                unsigned* __restrict__ cells,
                                unsigned* __restrict__ counts) {
    const float mnx = funkey(keys[0]), mny = funkey(keys[1]), mnz = funkey(keys[2]);
    const float mxx = funkey(keys[3]), mxy = funkey(keys[4]), mxz = funkey(keys[5]);
    const float sx = 47.0f / (mxx - mnx), sy = 47.0f / (mxy - mny), sz = 47.0f / (mxz - mnz);
    (void)sx; (void)sy; (void)sz;  // NOTE: must keep exact ref op order below
    int q = blockIdx.x * blockDim.x + threadIdx.x;
    int i0 = q * 4;
    if (i0 >= n) return;
    if (i0 + 4 <= n) {
        const float4* p4 = (const float4*)(xyz + (size_t)i0 * 3);
        float4 v0 = p4[0], v1 = p4[1], v2 = p4[2];
        float ax[4] = {v0.x, v0.w, v1.z, v2.y};
        float ay[4] = {v0.y, v1.x, v1.w, v2.z};
        float az[4] = {v0.z, v1.y, v2.x, v2.w};
        unsigned cc[4];
        #pragma unroll
        for (int k = 0; k < 4; k++) {
            unsigned cell = SENT;
            if (ax[k] != 0.f && ay[k] != 0.f && az[k] != 0.f) {
                // exact op-order of reference: (x - min) / (max - min) * 47, f32, trunc
                int cx = (int)((ax[k] - mnx) / (mxx - mnx) * 47.0f);
                int cy = (int)((ay[k] - mny) / (mxy - mny) * 47.0f);
                int cz = (int)((az[k] - mnz) / (mxz - mnz) * 47.0f);
                cell = (unsigned)((cz * VOL + cy) * VOL + cx);
                atomicAdd(&counts[cell], 1u);
            }
            cc[k] = cell;
        }
        *(uint4*)(cells + i0) = make_uint4(cc[0], cc[1], cc[2], cc[3]);
    } else {
        for (int i = i0; i < n; i++) {
            float x = xyz[3 * i], y = xyz[3 * i + 1], z = xyz[3 * i + 2];
            unsigned cell = SENT;
            if (x != 0.f && y != 0.f && z != 0.f) {
                int cx = (int)((x - mnx) / (mxx - mnx) * 47.0f);
                int cy = (int)((y - mny) / (mxy - mny) * 47.0f);
                int cz = (int)((z - mnz) / (mxz - mnz) * 47.0f);
                cell = (unsigned)((cz * VOL + cy) * VOL + cx);
                atomicAdd(&counts[cell], 1u);
            }
            cells[i] = cell;
        }
    }
}

// ---- stage 3a: block-level exclusive scan of counts ----
__global__ __launch_bounds__(SCB) void vox_scan_a(const unsigned* __restrict__ counts,
                                                  unsigned* __restrict__ offsets,
                                                  unsigned* __restrict__ bsums) {
    __shared__ unsigned s[SCB];
    int gid = blockIdx.x * SCB + threadIdx.x;
    unsigned c = counts[gid];
    s[threadIdx.x] = c;
    __syncthreads();
    for (int off = 1; off < SCB; off <<= 1) {
        unsigned v = 0;
        if ((int)threadIdx.x >= off) v = s[threadIdx.x - off];
        __syncthreads();
        if ((int)threadIdx.x >= off) s[threadIdx.x] += v;
        __syncthreads();
    }
    offsets[gid] = s[threadIdx.x] - c;          // exclusive within block
    if (threadIdx.x == SCB - 1) bsums[blockIdx.x] = s[threadIdx.x];
}

// ---- stage 3b: scan of the 432 block sums ----
__global__ __launch_bounds__(512) void vox_scan_b(unsigned* __restrict__ bsums,
                                                  unsigned* __restrict__ boffs) {
    __shared__ unsigned s[512];
    unsigned c = (threadIdx.x < NSB) ? bsums[threadIdx.x] : 0u;
    s[threadIdx.x] = c;
    __syncthreads();
    for (int off = 1; off < 512; off <<= 1) {
        unsigned v = 0;
        if ((int)threadIdx.x >= off) v = s[threadIdx.x - off];
        __syncthreads();
        if ((int)threadIdx.x >= off) s[threadIdx.x] += v;
        __syncthreads();
    }
    if (threadIdx.x < NSB) boffs[threadIdx.x] = s[threadIdx.x] - c;
}

// ---- stage 4: place atom indices into CSR slots (boffs fused in) ----
__global__ void vox_place(const unsigned* __restrict__ cells, int n,
                          unsigned* __restrict__ offsets,
                          const unsigned* __restrict__ boffs,
                          unsigned* __restrict__ order) {
    int q = blockIdx.x * blockDim.x + threadIdx.x;
    int i0 = q * 4;
    if (i0 >= n) return;
    if (i0 + 4 <= n) {
        uint4 cc = *(const uint4*)(cells + i0);
        unsigned arr[4] = {cc.x, cc.y, cc.z, cc.w};
        #pragma unroll
        for (int k = 0; k < 4; k++) {
            unsigned c = arr[k];
            if (c == SENT) continue;
            unsigned slot = boffs[c >> 8] + atomicAdd(&offsets[c], 1u);
            order[slot] = (unsigned)(i0 + k);
        }
    } else {
        for (int i = i0; i < n; i++) {
            unsigned c = cells[i];
            if (c == SENT) continue;
            unsigned slot = boffs[c >> 8] + atomicAdd(&offsets[c], 1u);
            order[slot] = (unsigned)i;
        }
    }
}

// ---- stage 5: per-cell feature accumulation, 8-deep MLP batching ----
__global__ __launch_bounds__(SCB) void vox_accum(const unsigned* __restrict__ order,
                                                 const unsigned* __restrict__ offsets,
                                                 const unsigned* __restrict__ counts,
                                                 const unsigned* __restrict__ boffs,
                                                 const float* __restrict__ feat,
                                                 float* __restrict__ center) {
    int cell = blockIdx.x * SCB + threadIdx.x;
    unsigned cnt = counts[cell];
    // offsets after place = intra-block-exclusive + cnt
    unsigned base = boffs[blockIdx.x] + offsets[cell] - cnt;
    float acc[FEATD];
    #pragma unroll
    for (int f = 0; f < FEATD; f++) acc[f] = 0.f;
    unsigned k = 0;
    while (k < cnt) {
        unsigned m = cnt - k; if (m > 8) m = 8;
        unsigned idx[8];
        // order[] is padded by 8 entries -> unguarded batch read, 8-deep MLP
        #pragma unroll
        for (int j = 0; j < 8; j++) idx[j] = order[base + k + j];
        #pragma unroll
        for (int j = 0; j < 8; j++) {
            if ((unsigned)j < m) {
                const float* fr = feat + (size_t)idx[j] * FEATD;
                #pragma unroll
                for (int f = 0; f < FEATD; f++) acc[f] += fr[f];
            }
        }
        k += m;
    }
    #pragma unroll
    for (int f = 0; f < FEATD; f++)
        center[(size_t)f * VOL3 + cell] = acc[f];
}

// ---- stage 6: 3x3x3 box conv; each thread does ZK z-outputs (rolling planes) ----
__global__ void vox_conv(const float* __restrict__ center, float* __restrict__ out) {
    int idx = blockIdx.x * blockDim.x + threadIdx.x;
    const int NT = FEATD * (VOL / ZK) * VOL * VOL;
    if (idx >= NT) return;
    int x = idx % VOL;
    int t = idx / VOL;
    int y = t % VOL;  t /= VOL;
    int zb = t % (VOL / ZK);
    int f = t / (VOL / ZK);
    const float* cf = center + (size_t)f * VOL3;

    int ylo = (y > 0) ? y - 1 : 0, yhi = (y < VOL - 1) ? y + 1 : VOL - 1;
    int xlo = (x > 0) ? x - 1 : 0, xhi = (x < VOL - 1) ? x + 1 : VOL - 1;
    auto psum = [&](int zz) -> float {
        if ((unsigned)zz >= (unsigned)VOL) return 0.f;
        float s = 0.f;
        for (int yy = ylo; yy <= yhi; yy++) {
            const float* row = cf + (zz * VOL + yy) * VOL;
            for (int xx = xlo; xx <= xhi; xx++) s += row[xx];
        }
        return s;
    };

    int z0 = zb * ZK;
    float Pm = psum(z0 - 1), Pc = psum(z0);
    #pragma unroll
    for (int k = 0; k < ZK; k++) {
        float Pn = psum(z0 + k + 1);
        out[(((size_t)f * VOL + (z0 + k)) * VOL + y) * VOL + x] = Pm + Pc + Pn;
        Pm = Pc; Pc = Pn;
    }
}

// ---- fallback: direct scatter (if ws too small) ----
__global__ void vox_scatter_lin(const float* __restrict__ xyz,
                                const float* __restrict__ feat, int n,
                                const unsigned* __restrict__ keys,
                                float* __restrict__ center) {
    int i = blockIdx.x * blockDim.x + threadIdx.x;
    if (i >= n) return;
    float x = xyz[3 * i], y = xyz[3 * i + 1], z = xyz[3 * i + 2];
    if (x == 0.f || y == 0.f || z == 0.f) return;
    float mnx = funkey(keys[0]), mny = funkey(keys[1]), mnz = funkey(keys[2]);
    float mxx = funkey(keys[3]), mxy = funkey(keys[4]), mxz = funkey(keys[5]);
    int cx = (int)((x - mnx) / (mxx - mnx) * 47.0f);
    int cy = (int)((y - mny) / (mxy - mny) * 47.0f);
    int cz = (int)((z - mnz) / (mxz - mnz) * 47.0f);
    int cell = (cz * VOL + cy) * VOL + cx;
    const float* fr = feat + (size_t)i * FEATD;
    #pragma unroll
    for (int f = 0; f < FEATD; f++)
        atomicAdd(&center[f * VOL3 + cell], fr[f]);
}

__global__ void vox_conv_flat(const float* __restrict__ center,
                              float* __restrict__ out, int total) {
    int idx = blockIdx.x * blockDim.x + threadIdx.x;
    if (idx >= total) return;
    int x = idx % VOL;
    int t = idx / VOL;
    int y = t % VOL;  t /= VOL;
    int z = t % VOL;
    int f = t / VOL;
    const float* cf = center + (size_t)f * VOL3;
    float s = 0.f;
    for (int dz = -1; dz <= 1; dz++) {
        int zz = z + dz; if ((unsigned)zz >= (unsigned)VOL) continue;
        for (int dy = -1; dy <= 1; dy++) {
            int yy = y + dy; if ((unsigned)yy >= (unsigned)VOL) continue;
            const float* row = cf + (zz * VOL + yy) * VOL;
            #pragma unroll
            for (int dx = -1; dx <= 1; dx++) {
                int xx = x + dx; if ((unsigned)xx >= (unsigned)VOL) continue;
                s += row[xx];
            }
        }
    }
    out[idx] = s;
}

extern "C" void kernel_launch(void* const* d_in, const int* in_sizes, int n_in,
                              void* d_out, int out_size, void* d_ws, size_t ws_size,
                              hipStream_t stream) {
    const float* xyz  = (const float*)d_in[0];
    const float* feat = (const float*)d_in[1];
    float* out = (float*)d_out;
    int n = in_sizes[0] / 3;

    char* w = (char*)d_ws;
    unsigned* keys    = (unsigned*)w;                       // 24 B (pad 256)
    unsigned* cells   = (unsigned*)(w + 256);               // n*4
    size_t o1 = 256 + (size_t)n * 4;
    unsigned* counts  = (unsigned*)(w + o1);                // VOL3*4
    size_t o2 = o1 + (size_t)VOL3 * 4;
    unsigned* offsets = (unsigned*)(w + o2);                // VOL3*4
    size_t o3 = o2 + (size_t)VOL3 * 4;
    unsigned* bsums   = (unsigned*)(w + o3);                // 512*4
    unsigned* boffs   = bsums + 512;                        // 512*4
    size_t o4 = o3 + 4096;
    unsigned* order   = (unsigned*)(w + o4);                // (n+8)*4 (padded)
    size_t o5 = o4 + (size_t)(n + 8) * 4;
    float* center     = (float*)(w + o5);                   // FEATD*VOL3*4
    size_t need = o5 + (size_t)FEATD * VOL3 * 4;

    const int b = 256;

    if (ws_size >= need) {
        vox_init<<<1, 64, 0, stream>>>(keys);
        vox_minmax<<<64, 1024, 0, stream>>>(xyz, n, keys, counts);
        int nq = (n + 3) / 4;
        vox_cells_count<<<(nq + b - 1) / b, b, 0, stream>>>(xyz, n, keys, cells, counts);
        vox_scan_a<<<NSB, SCB, 0, stream>>>(counts, offsets, bsums);
        vox_scan_b<<<1, 512, 0, stream>>>(bsums, boffs);
        vox_place<<<(nq + b - 1) / b, b, 0, stream>>>(cells, n, offsets, boffs, order);
        vox_accum<<<NSB, SCB, 0, stream>>>(order, offsets, counts, boffs, feat, center);
        const int nconv = FEATD * (VOL / ZK) * VOL * VOL;
        vox_conv<<<(nconv + b - 1) / b, b, 0, stream>>>(center, out);
    } else {
        float* c2 = (float*)(w + 256);
        vox_init<<<1, 64, 0, stream>>>(keys);
        vox_minmax<<<64, 1024, 0, stream>>>(xyz, n, keys, c2 ? (unsigned*)c2 : nullptr);
        hipMemsetAsync(c2, 0, (size_t)FEATD * VOL3 * 4, stream);
        vox_scatter_lin<<<(n + b - 1) / b, b, 0, stream>>>(xyz, feat, n, keys, c2);
        const int total = FEATD * VOL3;
        vox_conv_flat<<<(total + b - 1) / b, b, 0, stream>>>(c2, out, total);
    }
}

// Round 6
// 73.874 us; speedup vs baseline: 6.8208x; 1.2879x over previous
//
#include <hip/hip_runtime.h>

// Voxelizer3D: out[f][z][y][x] = sum over masked atoms (all coords != 0) whose
// center cell is within Chebyshev distance 1 of (x,y,z), of feat[a][f].
// v6: 4-dispatch bucket pipeline (no scan, no place, no key atomics).
//   minmax_p (partials + zero counts) -> scatter_bucket (fused cell+count+place)
//   -> accum (8-deep MLP gather, overflow merge) -> conv (rolling-z box conv).

constexpr int VOL   = 48;
constexpr int FEATD = 19;
constexpr int VOL3  = VOL * VOL * VOL;      // 110592
constexpr int CAP   = 128;                  // bucket capacity per cell
constexpr int OVCAP = 8192;                 // overflow list capacity (cold)
constexpr int NMB   = 64;                   // minmax partial blocks
constexpr int SCB   = 256;
constexpr int NSB   = VOL3 / SCB;           // 432
constexpr int ZK    = 4;                    // z outputs per conv thread

__device__ __forceinline__ unsigned fkey(float f) {
    unsigned u = __float_as_uint(f);
    return (u & 0x80000000u) ? ~u : (u | 0x80000000u);
}
__device__ __forceinline__ float funkey(unsigned k) {
    unsigned u = (k & 0x80000000u) ? (k & 0x7fffffffu) : ~k;
    return __uint_as_float(u);
}

// ---- K1: per-block min/max partials; zero counts + ovf counter ----
__global__ __launch_bounds__(1024) void vox_minmax_p(const float* __restrict__ xyz,
                                                     int n, unsigned* __restrict__ pb,
                                                     unsigned* __restrict__ counts,
                                                     unsigned* __restrict__ ovf_cnt) {
    int gid = blockIdx.x * blockDim.x + threadIdx.x;
    for (int j = gid; j < VOL3; j += gridDim.x * blockDim.x) counts[j] = 0u;
    if (gid == 0) *ovf_cnt = 0u;

    __shared__ unsigned smin[16][3], smax[16][3];
    unsigned kmin[3] = {~0u, ~0u, ~0u};
    unsigned kmax[3] = {0u, 0u, 0u};
    const int nq = n >> 2;
    const float4* p4 = (const float4*)xyz;
    for (int q = gid; q < nq; q += gridDim.x * blockDim.x) {
        float4 v0 = p4[3 * q], v1 = p4[3 * q + 1], v2 = p4[3 * q + 2];
        float ax[4] = {v0.x, v0.w, v1.z, v2.y};
        float ay[4] = {v0.y, v1.x, v1.w, v2.z};
        float az[4] = {v0.z, v1.y, v2.x, v2.w};
        #pragma unroll
        for (int k = 0; k < 4; k++) {
            if (ax[k] != 0.f && ay[k] != 0.f && az[k] != 0.f) {
                unsigned kk[3] = {fkey(ax[k]), fkey(ay[k]), fkey(az[k])};
                #pragma unroll
                for (int c = 0; c < 3; c++) {
                    kmin[c] = kmin[c] < kk[c] ? kmin[c] : kk[c];
                    kmax[c] = kmax[c] > kk[c] ? kmax[c] : kk[c];
                }
            }
        }
    }
    for (int i = (nq << 2) + gid; i < n; i += gridDim.x * blockDim.x) {
        float x = xyz[3 * i], y = xyz[3 * i + 1], z = xyz[3 * i + 2];
        if (x != 0.f && y != 0.f && z != 0.f) {
            unsigned kk[3] = {fkey(x), fkey(y), fkey(z)};
            #pragma unroll
            for (int c = 0; c < 3; c++) {
                kmin[c] = kmin[c] < kk[c] ? kmin[c] : kk[c];
                kmax[c] = kmax[c] > kk[c] ? kmax[c] : kk[c];
            }
        }
    }
    #pragma unroll
    for (int o = 32; o; o >>= 1) {
        #pragma unroll
        for (int c = 0; c < 3; c++) {
            unsigned omin = __shfl_xor(kmin[c], o, 64);
            unsigned omax = __shfl_xor(kmax[c], o, 64);
            kmin[c] = kmin[c] < omin ? kmin[c] : omin;
            kmax[c] = kmax[c] > omax ? kmax[c] : omax;
        }
    }
    int wave = threadIdx.x >> 6;
    if ((threadIdx.x & 63) == 0) {
        #pragma unroll
        for (int c = 0; c < 3; c++) { smin[wave][c] = kmin[c]; smax[wave][c] = kmax[c]; }
    }
    __syncthreads();
    if (threadIdx.x == 0) {
        int nw = blockDim.x >> 6;
        #pragma unroll
        for (int c = 0; c < 3; c++) { kmin[c] = smin[0][c]; kmax[c] = smax[0][c]; }
        for (int w = 1; w < nw; w++) {
            #pragma unroll
            for (int c = 0; c < 3; c++) {
                kmin[c] = kmin[c] < smin[w][c] ? kmin[c] : smin[w][c];
                kmax[c] = kmax[c] > smax[w][c] ? kmax[c] : smax[w][c];
            }
        }
        #pragma unroll
        for (int c = 0; c < 3; c++) {
            pb[blockIdx.x * 6 + c]     = kmin[c];
            pb[blockIdx.x * 6 + 3 + c] = kmax[c];
        }
    }
}

// reduce the NMB partials -> 6 floats, broadcast via LDS (called inside kernels)
__device__ __forceinline__ void reduce_keys(const unsigned* __restrict__ pb,
                                            float* __restrict__ sm) {
    if (threadIdx.x < 64) {
        unsigned mn[3], mx[3];
        int t = threadIdx.x;
        bool live = t < NMB;
        #pragma unroll
        for (int c = 0; c < 3; c++) {
            mn[c] = live ? pb[t * 6 + c]     : ~0u;
            mx[c] = live ? pb[t * 6 + 3 + c] : 0u;
        }
        #pragma unroll
        for (int o = 32; o; o >>= 1) {
            #pragma unroll
            for (int c = 0; c < 3; c++) {
                unsigned omin = __shfl_xor(mn[c], o, 64);
                unsigned omax = __shfl_xor(mx[c], o, 64);
                mn[c] = mn[c] < omin ? mn[c] : omin;
                mx[c] = mx[c] > omax ? mx[c] : omax;
            }
        }
        if (t == 0) {
            #pragma unroll
            for (int c = 0; c < 3; c++) { sm[c] = funkey(mn[c]); sm[3 + c] = funkey(mx[c]); }
        }
    }
    __syncthreads();
}

// ---- K2: fused cell-compute + count + bucket-place (4 atoms/thread) ----
__global__ __launch_bounds__(SCB) void vox_scatter(const float* __restrict__ xyz, int n,
                                                   const unsigned* __restrict__ pb,
                                                   unsigned* __restrict__ counts,
                                                   unsigned* __restrict__ bucket,
                                                   unsigned* __restrict__ ovf,
                                                   unsigned* __restrict__ ovf_cnt) {
    __shared__ float sm[6];
    reduce_keys(pb, sm);
    const float mnx = sm[0], mny = sm[1], mnz = sm[2];
    const float mxx = sm[3], mxy = sm[4], mxz = sm[5];

    int q = blockIdx.x * blockDim.x + threadIdx.x;
    int i0 = q * 4;
    if (i0 >= n) return;
    float ax[4], ay[4], az[4];
    int cnt4 = 4;
    if (i0 + 4 <= n) {
        const float4* p4 = (const float4*)(xyz + (size_t)i0 * 3);
        float4 v0 = p4[0], v1 = p4[1], v2 = p4[2];
        ax[0]=v0.x; ax[1]=v0.w; ax[2]=v1.z; ax[3]=v2.y;
        ay[0]=v0.y; ay[1]=v1.x; ay[2]=v1.w; ay[3]=v2.z;
        az[0]=v0.z; az[1]=v1.y; az[2]=v2.x; az[3]=v2.w;
    } else {
        cnt4 = n - i0;
        for (int k = 0; k < cnt4; k++) {
            ax[k] = xyz[3 * (i0 + k)]; ay[k] = xyz[3 * (i0 + k) + 1]; az[k] = xyz[3 * (i0 + k) + 2];
        }
    }
    #pragma unroll
    for (int k = 0; k < 4; k++) {
        if (k >= cnt4) break;
        if (ax[k] == 0.f || ay[k] == 0.f || az[k] == 0.f) continue;
        // exact op-order of reference: (x - min) / (max - min) * 47, f32, trunc
        int cx = (int)((ax[k] - mnx) / (mxx - mnx) * 47.0f);
        int cy = (int)((ay[k] - mny) / (mxy - mny) * 47.0f);
        int cz = (int)((az[k] - mnz) / (mxz - mnz) * 47.0f);
        unsigned cell = (unsigned)((cz * VOL + cy) * VOL + cx);
        unsigned slot = atomicAdd(&counts[cell], 1u);
        if (slot < CAP) {
            bucket[(size_t)cell * CAP + slot] = (unsigned)(i0 + k);
        } else {
            unsigned j = atomicAdd(ovf_cnt, 1u);
            if (j < OVCAP) { ovf[2 * j] = cell; ovf[2 * j + 1] = (unsigned)(i0 + k); }
        }
    }
}

// ---- K3: per-cell feature accumulation, 8-deep MLP batching ----
__global__ __launch_bounds__(SCB) void vox_accum(const unsigned* __restrict__ bucket,
                                                 const unsigned* __restrict__ counts,
                                                 const unsigned* __restrict__ ovf,
                                                 const unsigned* __restrict__ ovf_cnt,
                                                 const float* __restrict__ feat,
                                                 float* __restrict__ center) {
    int cell = blockIdx.x * SCB + threadIdx.x;
    unsigned cnt = counts[cell];
    unsigned use = cnt < CAP ? cnt : CAP;
    const unsigned* b = bucket + (size_t)cell * CAP;
    float acc[FEATD];
    #pragma unroll
    for (int f = 0; f < FEATD; f++) acc[f] = 0.f;
    unsigned k = 0;
    while (k < use) {
        unsigned m = use - k; if (m > 8) m = 8;
        unsigned idx[8];
        #pragma unroll
        for (int j = 0; j < 8; j++) idx[j] = b[(k + j) < CAP ? (k + j) : (CAP - 1)];
        #pragma unroll
        for (int j = 0; j < 8; j++) {
            if ((unsigned)j < m) {
                const float* fr = feat + (size_t)idx[j] * FEATD;
                #pragma unroll
                for (int f = 0; f < FEATD; f++) acc[f] += fr[f];
            }
        }
        k += m;
    }
    if (cnt > CAP) {   // cold overflow merge (never taken for this data)
        unsigned no = *ovf_cnt; if (no > OVCAP) no = OVCAP;
        for (unsigned i = 0; i < no; i++) {
            if (ovf[2 * i] == (unsigned)cell) {
                const float* fr = feat + (size_t)ovf[2 * i + 1] * FEATD;
                #pragma unroll
                for (int f = 0; f < FEATD; f++) acc[f] += fr[f];
            }
        }
    }
    #pragma unroll
    for (int f = 0; f < FEATD; f++)
        center[(size_t)f * VOL3 + cell] = acc[f];
}

// ---- K4: 3x3x3 box conv; each thread does ZK z-outputs (rolling planes) ----
__global__ void vox_conv(const float* __restrict__ center, float* __restrict__ out) {
    int idx = blockIdx.x * blockDim.x + threadIdx.x;
    const int NT = FEATD * (VOL / ZK) * VOL * VOL;
    if (idx >= NT) return;
    int x = idx % VOL;
    int t = idx / VOL;
    int y = t % VOL;  t /= VOL;
    int zb = t % (VOL / ZK);
    int f = t / (VOL / ZK);
    const float* cf = center + (size_t)f * VOL3;

    int ylo = (y > 0) ? y - 1 : 0, yhi = (y < VOL - 1) ? y + 1 : VOL - 1;
    int xlo = (x > 0) ? x - 1 : 0, xhi = (x < VOL - 1) ? x + 1 : VOL - 1;
    auto psum = [&](int zz) -> float {
        if ((unsigned)zz >= (unsigned)VOL) return 0.f;
        float s = 0.f;
        for (int yy = ylo; yy <= yhi; yy++) {
            const float* row = cf + (zz * VOL + yy) * VOL;
            for (int xx = xlo; xx <= xhi; xx++) s += row[xx];
        }
        return s;
    };

    int z0 = zb * ZK;
    float Pm = psum(z0 - 1), Pc = psum(z0);
    #pragma unroll
    for (int k = 0; k < ZK; k++) {
        float Pn = psum(z0 + k + 1);
        out[(((size_t)f * VOL + (z0 + k)) * VOL + y) * VOL + x] = Pm + Pc + Pn;
        Pm = Pc; Pc = Pn;
    }
}

// ---- fallback path (ws too small): keys reduce + direct scatter + flat conv ----
__global__ void vox_keys(const unsigned* __restrict__ pb, unsigned* __restrict__ keys) {
    __shared__ float sm[6];
    reduce_keys(pb, sm);
    if (threadIdx.x < 6) keys[threadIdx.x] = __float_as_uint(sm[threadIdx.x]);
}
__global__ void vox_scatter_lin(const float* __restrict__ xyz,
                                const float* __restrict__ feat, int n,
                                const unsigned* __restrict__ keys,
                                float* __restrict__ center) {
    int i = blockIdx.x * blockDim.x + threadIdx.x;
    if (i >= n) return;
    float x = xyz[3 * i], y = xyz[3 * i + 1], z = xyz[3 * i + 2];
    if (x == 0.f || y == 0.f || z == 0.f) return;
    float mnx = __uint_as_float(keys[0]), mny = __uint_as_float(keys[1]), mnz = __uint_as_float(keys[2]);
    float mxx = __uint_as_float(keys[3]), mxy = __uint_as_float(keys[4]), mxz = __uint_as_float(keys[5]);
    int cx = (int)((x - mnx) / (mxx - mnx) * 47.0f);
    int cy = (int)((y - mny) / (mxy - mny) * 47.0f);
    int cz = (int)((z - mnz) / (mxz - mnz) * 47.0f);
    int cell = (cz * VOL + cy) * VOL + cx;
    const float* fr = feat + (size_t)i * FEATD;
    #pragma unroll
    for (int f = 0; f < FEATD; f++)
        atomicAdd(&center[f * VOL3 + cell], fr[f]);
}
__global__ void vox_conv_flat(const float* __restrict__ center,
                              float* __restrict__ out, int total) {
    int idx = blockIdx.x * blockDim.x + threadIdx.x;
    if (idx >= total) return;
    int x = idx % VOL;
    int t = idx / VOL;
    int y = t % VOL;  t /= VOL;
    int z = t % VOL;
    int f = t / VOL;
    const float* cf = center + (size_t)f * VOL3;
    float s = 0.f;
    for (int dz = -1; dz <= 1; dz++) {
        int zz = z + dz; if ((unsigned)zz >= (unsigned)VOL) continue;
        for (int dy = -1; dy <= 1; dy++) {
            int yy = y + dy; if ((unsigned)yy >= (unsigned)VOL) continue;
            const float* row = cf + (zz * VOL + yy) * VOL;
            #pragma unroll
            for (int dx = -1; dx <= 1; dx++) {
                int xx = x + dx; if ((unsigned)xx >= (unsigned)VOL) continue;
                s += row[xx];
            }
        }
    }
    out[idx] = s;
}

extern "C" void kernel_launch(void* const* d_in, const int* in_sizes, int n_in,
                              void* d_out, int out_size, void* d_ws, size_t ws_size,
                              hipStream_t stream) {
    const float* xyz  = (const float*)d_in[0];
    const float* feat = (const float*)d_in[1];
    float* out = (float*)d_out;
    int n = in_sizes[0] / 3;

    char* w = (char*)d_ws;
    unsigned* pb      = (unsigned*)w;                        // NMB*6 u32 = 1536 B
    unsigned* ovf_cnt = (unsigned*)(w + 1536);               // 4 B (pad to 2048)
    unsigned* counts  = (unsigned*)(w + 2048);               // VOL3*4 = 442368
    size_t o3 = 2048 + (size_t)VOL3 * 4;                     // 444416 (256-aligned)
    unsigned* bucket  = (unsigned*)(w + o3);                 // VOL3*CAP*4 = 56.6 MB
    size_t o4 = o3 + (size_t)VOL3 * CAP * 4;
    float* center     = (float*)(w + o4);                    // FEATD*VOL3*4 = 8.4 MB
    size_t o5 = o4 + (size_t)FEATD * VOL3 * 4;
    unsigned* ovf     = (unsigned*)(w + o5);                 // 2*OVCAP*4 = 64 KB
    size_t need = o5 + (size_t)2 * OVCAP * 4;

    const int b = SCB;
    int nq = (n + 3) / 4;

    if (ws_size >= need) {
        vox_minmax_p<<<NMB, 1024, 0, stream>>>(xyz, n, pb, counts, ovf_cnt);
        vox_scatter<<<(nq + b - 1) / b, b, 0, stream>>>(xyz, n, pb, counts, bucket, ovf, ovf_cnt);
        vox_accum<<<NSB, SCB, 0, stream>>>(bucket, counts, ovf, ovf_cnt, feat, center);
        const int nconv = FEATD * (VOL / ZK) * VOL * VOL;
        vox_conv<<<(nconv + b - 1) / b, b, 0, stream>>>(center, out);
    } else {
        unsigned* keys = (unsigned*)(w + 1536 + 64);
        float* c2 = (float*)(w + 4096);
        vox_minmax_p<<<NMB, 1024, 0, stream>>>(xyz, n, pb, counts, ovf_cnt);
        vox_keys<<<1, 64, 0, stream>>>(pb, keys);
        hipMemsetAsync(c2, 0, (size_t)FEATD * VOL3 * 4, stream);
        vox_scatter_lin<<<(n + b - 1) / b, b, 0, stream>>>(xyz, feat, n, keys, c2);
        const int total = FEATD * VOL3;
        vox_conv_flat<<<(total + b - 1) / b, b, 0, stream>>>(c2, out, total);
    }
}